// Round 7
// baseline (979.799 us; speedup 1.0000x reference)
//
#include <hip/hip_runtime.h>
#include <hip/hip_bf16.h>
#include <math.h>

typedef __hip_bfloat16 bf16;
typedef __attribute__((ext_vector_type(8))) short bf16x8;   // 8 bf16 = 4 VGPRs (MFMA A/B frag)
typedef __attribute__((ext_vector_type(4))) short bf16x4;   // 4 bf16 = 8 bytes
typedef __attribute__((ext_vector_type(4))) float f32x4;    // MFMA C/D frag

__device__ __forceinline__ void glds16(const bf16* g, bf16* l) {
    __builtin_amdgcn_global_load_lds(
        (const __attribute__((address_space(1))) void*)g,
        (__attribute__((address_space(3))) void*)l, 16, 0, 0);
}

// ---------------------------------------------------------------------------
// Self-detecting convert: each wave inspects the tensor's first 128 ushorts.
// ---------------------------------------------------------------------------
__global__ __launch_bounds__(256)
void convert_to_bf16(const void* __restrict__ src, bf16* __restrict__ dst, long n) {
    const unsigned short* u16 = (const unsigned short*)src;
    int lane = threadIdx.x & 63;
    unsigned short u = u16[lane * 2];
    int e = (u >> 7) & 0xFF;
    int isf32 = __popcll(__ballot(e >= 0x86)) > 4;   // wave-uniform
    long i = ((long)blockIdx.x * 256 + threadIdx.x) * 8;
    if (i >= n) return;
    if (isf32) {
        const float* s = (const float*)src;
        bf16x8 o;
        #pragma unroll
        for (int j = 0; j < 8; j++) {
            bf16 b = (bf16)s[i + j];
            o[j] = *(short*)&b;
        }
        *(bf16x8*)(dst + i) = o;
    } else {
        *(bf16x8*)(dst + i) = *(const bf16x8*)((const bf16*)src + i);
    }
}

// ---------------------------------------------------------------------------
// GEMM (round 6, verified): 256xBN tile, BK=64, 8 waves, dbuf LDS, counted
// vmcnt/lgkm pipeline, T2 source-side swizzle (0 conflicts), T1, T5.
// ---------------------------------------------------------------------------
template<int BN, bool CLIP, typename OUT>
__global__ __launch_bounds__(512, 2)
void gemm256(const bf16* __restrict__ A, const bf16* __restrict__ B,
             OUT* __restrict__ C, int M, int N, int K) {
    constexpr int NB = BN / 64;          // B frags per k-step, B stage issues
    constexpr int WN = BN / 4;           // per-wave N span
    __shared__ __align__(16) bf16 sA[2][256 * 64];
    __shared__ __align__(16) bf16 sB[2][BN * 64];

    const int tid   = threadIdx.x;
    const int lane  = tid & 63;
    const int row16 = lane & 15;
    const int quad  = lane >> 4;
    const int wid   = tid >> 6;
    const int wr    = wid >> 2;          // 0..1  (M half)
    const int wc    = wid & 3;           // 0..3  (N quarter)

    // T1: XCD-aware bijective swizzle (grids here are multiples of 8)
    const int nwg  = gridDim.x * gridDim.y;
    const int orig = blockIdx.y * gridDim.x + blockIdx.x;
    const int cpx  = nwg >> 3;
    const int sw   = (orig & 7) * cpx + (orig >> 3);
    const int bn   = sw % gridDim.x;
    const int bm   = sw / gridDim.x;

    // Staging: linear LDS dest (tid*16 B), source chunk = slot ^ (row&7).
    const int srow   = tid >> 3;                 // 0..63
    const int schunk = (tid & 7) ^ (srow & 7);
    const bf16* gA = A + (size_t)(bm * 256) * K + schunk * 8;
    const bf16* gB = B + (size_t)(bn * BN) * K + schunk * 8;

    auto STAGE = [&](int u, int t) {
        #pragma unroll
        for (int q = 0; q < 4; q++)
            glds16(gA + (size_t)(q * 64 + srow) * K + t * 64,
                   &sA[u][0] + q * 4096 + tid * 8);
        #pragma unroll
        for (int q = 0; q < NB; q++)
            glds16(gB + (size_t)(q * 64 + srow) * K + t * 64,
                   &sB[u][0] + q * 4096 + tid * 8);
    };

    // Fragment read bases (bytes); chunk c of row r sits at slot c^(r&7).
    const int cx0 = ((quad) ^ (row16 & 7)) << 4;
    const int cx1 = ((4 + quad) ^ (row16 & 7)) << 4;
    const int aRowOff = (wr * 128 + row16) * 128;
    const int bRowOff = (wc * WN + row16) * 128;

    f32x4 acc[8][NB] = {};

    const int NT = K >> 6;               // 64-wide K-tiles
    STAGE(0, 0);
    STAGE(1, 1);
    if constexpr (NB == 4) asm volatile("s_waitcnt vmcnt(8)" ::: "memory");
    else                   asm volatile("s_waitcnt vmcnt(7)" ::: "memory");
    __builtin_amdgcn_sched_barrier(0);
    __builtin_amdgcn_s_barrier();

    for (int t = 0; t < NT; t++) {
        const int cur = t & 1;
        const char* aRd = (const char*)(&sA[cur][0]) + aRowOff;
        const char* bRd = (const char*)(&sB[cur][0]) + bRowOff;

        // issue ks0 reads (8+NB), then ks1 reads (8+NB), order pinned
        bf16x8 af0[8], bf0[NB], af1[8], bf1[NB];
        #pragma unroll
        for (int i = 0; i < 8; i++)
            af0[i] = *(const bf16x8*)(aRd + i * 2048 + cx0);
        #pragma unroll
        for (int j = 0; j < NB; j++)
            bf0[j] = *(const bf16x8*)(bRd + j * 2048 + cx0);
        __builtin_amdgcn_sched_barrier(0);      // group boundary (lgkm count!)
        #pragma unroll
        for (int i = 0; i < 8; i++)
            af1[i] = *(const bf16x8*)(aRd + i * 2048 + cx1);
        #pragma unroll
        for (int j = 0; j < NB; j++)
            bf1[j] = *(const bf16x8*)(bRd + j * 2048 + cx1);
        __builtin_amdgcn_sched_barrier(0);

        // wait first group only (DS completes in-order per wave)
        if constexpr (NB == 4) asm volatile("s_waitcnt lgkmcnt(12)" ::: "memory");
        else                   asm volatile("s_waitcnt lgkmcnt(11)" ::: "memory");
        __builtin_amdgcn_sched_barrier(0);

        __builtin_amdgcn_s_setprio(1);
        #pragma unroll
        for (int i = 0; i < 8; i++)
            #pragma unroll
            for (int j = 0; j < NB; j++)
                acc[i][j] = __builtin_amdgcn_mfma_f32_16x16x32_bf16(
                    af0[i], bf0[j], acc[i][j], 0, 0, 0);
        __builtin_amdgcn_s_setprio(0);
        __builtin_amdgcn_sched_barrier(0);

        asm volatile("s_waitcnt lgkmcnt(0)" ::: "memory");
        __builtin_amdgcn_sched_barrier(0);
        __builtin_amdgcn_s_barrier();        // all waves done reading buf[cur]

        if (t + 2 < NT) STAGE(cur, t + 2);
        __builtin_amdgcn_sched_barrier(0);   // keep glds issued before MFMA

        __builtin_amdgcn_s_setprio(1);
        #pragma unroll
        for (int i = 0; i < 8; i++)
            #pragma unroll
            for (int j = 0; j < NB; j++)
                acc[i][j] = __builtin_amdgcn_mfma_f32_16x16x32_bf16(
                    af1[i], bf1[j], acc[i][j], 0, 0, 0);
        __builtin_amdgcn_s_setprio(0);
        __builtin_amdgcn_sched_barrier(0);

        if (t + 2 < NT) {
            if constexpr (NB == 4) asm volatile("s_waitcnt vmcnt(8)" ::: "memory");
            else                   asm volatile("s_waitcnt vmcnt(7)" ::: "memory");
        } else {
            asm volatile("s_waitcnt vmcnt(0)" ::: "memory");
        }
        __builtin_amdgcn_sched_barrier(0);
        __builtin_amdgcn_s_barrier();        // buf[cur^1] (tile t+1) visible
    }

    // epilogue: C/D layout col = lane&15, row = quad*4+v  [m89/m91]
    #pragma unroll
    for (int i = 0; i < 8; i++) {
        #pragma unroll
        for (int j = 0; j < NB; j++) {
            #pragma unroll
            for (int v = 0; v < 4; v++) {
                float val = acc[i][j][v];
                if (CLIP) val = fminf(fmaxf(val, -8.0f), 8.0f);
                int grow = bm * 256 + wr * 128 + i * 16 + quad * 4 + v;
                int gcol = bn * BN + wc * WN + j * 16 + row16;
                C[(size_t)grow * N + gcol] = (OUT)val;
            }
        }
    }
}

// ---------------------------------------------------------------------------
// RoPE + reorder: qkv[token][6144] -> Q[b][32][l][128] (roped),
// K[b][8][l][128] (roped), VT[b][8][128][l] (transposed copy).
// ---------------------------------------------------------------------------
__global__ __launch_bounds__(256)
void rope_reorder(const bf16* __restrict__ qkv, bf16* __restrict__ Q,
                  bf16* __restrict__ Kd, bf16* __restrict__ VT) {
    const int token = blockIdx.y;                          // 0..4095
    const int slot  = blockIdx.x * 4 + (threadIdx.x >> 6); // 0..47
    const int lane  = threadIdx.x & 63;
    const int b = token >> 11, l = token & 2047;
    const bf16* src = qkv + (size_t)token * 6144 + slot * 128;
    if (slot < 40) {
        float x1 = __bfloat162float(src[lane]);
        float x2 = __bfloat162float(src[lane + 64]);
        float inv_freq = powf(500000.0f, -(float)lane * (1.0f / 64.0f));
        float ang = (float)l * inv_freq;
        float s, c;
        sincosf(ang, &s, &c);
        float o1 = x1 * c - x2 * s;
        float o2 = x2 * c + x1 * s;
        bf16* dst;
        if (slot < 32) dst = Q  + ((size_t)(b * 32 + slot)        * 2048 + l) * 128;
        else           dst = Kd + ((size_t)(b * 8  + (slot - 32)) * 2048 + l) * 128;
        dst[lane]      = (bf16)o1;
        dst[lane + 64] = (bf16)o2;
    } else {
        bf16* dst = VT + (size_t)(b * 8 + (slot - 40)) * 128 * 2048 + l;
        dst[(size_t)lane * 2048]        = src[lane];
        dst[(size_t)(lane + 64) * 2048] = src[lane + 64];
    }
}

// ---------------------------------------------------------------------------
// Flash attention, causal, GQA 4:1. Round 7: 8 waves / 128-row Q tiles.
// Per-wave structure identical to round 4 (16 q-rows, swapped QK^T,
// in-register softmax, T13 defer-max, T14 reg staging, source swizzle), but:
//   - 512 threads share one 64-kpos K/V tile -> staging per wave HALVES
//     (kpf[2]/vpf[2]); K/V fetch per q-row halves; LDS 48KB -> 3 blocks/CU
//     = 24 waves/CU = 6 waves/SIMD (2x the latency hiding).
//   - sP XOR-swizzled (slot^(row&7), 128B rows) -> kills the 1.19e7
//     conflicts traced to the unswizzled stride-144 sP reads.
//   - exact causal mask on straddling tiles; wave-uniform skip of fully
//     masked tiles (barrier/staging path stays uniform).
//   - LPT on grid Y (slow dim): all qt=15 blocks dispatch first globally.
// ---------------------------------------------------------------------------
__global__ __launch_bounds__(512, 6)
void attn_kernel(const bf16* __restrict__ Q, const bf16* __restrict__ K,
                 const bf16* __restrict__ V, bf16* __restrict__ Oout) {
    const int qt = 15 - blockIdx.y;     // LPT: big tiles first (global)
    const int bh = blockIdx.x;          // 0..63
    const int b = bh >> 5, h = bh & 31;
    const int kh = h >> 2;              // GQA: head h uses kv-head h/4
    const bf16* Qp = Q + ((size_t)(b * 32 + h) * 2048 + qt * 128) * 128;
    const bf16* Kp = K + (size_t)(b * 8 + kh) * 2048 * 128;
    const bf16* Vp = V + (size_t)(b * 8 + kh) * 128 * 2048;   // [d][l]

    __shared__ __align__(16) bf16 sK[64 * 128];    // 16 KB, source-swizzled
    __shared__ __align__(16) bf16 sV[128 * 64];    // 16 KB, source-swizzled
    __shared__ __align__(16) bf16 sP[8 * 16 * 64]; // 16 KB, XOR-swizzled

    const int tid = threadIdx.x, lane = tid & 63, wave = tid >> 6;
    const int row = lane & 15, quad = lane >> 4;
    const int rx  = (row & 7) << 4;      // read-side XOR (byte bits 4..6)
    char* sKb = (char*)sK;
    char* sVb = (char*)sV;
    char* sPb = (char*)sP;

    // Staging (512 threads, 2 passes each): linear LDS dest, swizzled source.
    // K: pass j covers rows j*32+(tid>>4), slot tid&15; (row&7) is j-invariant.
    // V: pass j covers rows j*64+(tid>>3), slot tid&7.
    const int kr0 = tid >> 4;
    const int kc8 = (tid & 15) ^ (kr0 & 7);
    const int vr0 = tid >> 3;
    const int vc8 = (tid & 7) ^ (vr0 & 7);
    const int ldst = tid * 16;
    const bf16* kga = Kp + (size_t)kr0 * 128 + kc8 * 8;   // + jj*8192 (+4096 pass1)
    const bf16* vga = Vp + (size_t)vr0 * 2048 + vc8 * 8;  // + jj*64  (+131072 pass1)

    // Q fragments straight to registers (this wave's 16 q-rows), read once.
    bf16x8 aq[4];
    #pragma unroll
    for (int kk = 0; kk < 4; kk++)
        aq[kk] = *(const bf16x8*)(Qp + (size_t)(wave * 16 + row) * 128 + (kk * 4 + quad) * 8);

    // prologue: stage tile 0
    bf16x8 kpf[2], vpf[2];
    kpf[0] = *(const bf16x8*)(kga);
    kpf[1] = *(const bf16x8*)(kga + 4096);
    vpf[0] = *(const bf16x8*)(vga);
    vpf[1] = *(const bf16x8*)(vga + 131072);
    *(bf16x8*)(sKb + ldst)        = kpf[0];
    *(bf16x8*)(sKb + ldst + 8192) = kpf[1];
    *(bf16x8*)(sVb + ldst)        = vpf[0];
    *(bf16x8*)(sVb + ldst + 8192) = vpf[1];
    __syncthreads();

    float pm = -1e30f, pl = 0.0f;       // per-lane stats for q-row lane&15
    f32x4 o_acc[8] = {};
    const float scale = 0.08838834764831845f;   // 1/sqrt(128)
    const int NJ = 2 * qt + 2;
    const int qrow_lane = qt * 128 + wave * 16 + row;   // this lane's q-row
    const int qrow_wmin = qt * 128 + wave * 16;
    const int qrow_wmax = qrow_wmin + 15;

    for (int jj = 0; jj < NJ; jj++) {
        // T14: issue next tile's loads EARLY (used only after the barrier)
        if (jj < NJ - 1) {
            kpf[0] = *(const bf16x8*)(kga + (size_t)(jj + 1) * 8192);
            kpf[1] = *(const bf16x8*)(kga + (size_t)(jj + 1) * 8192 + 4096);
            vpf[0] = *(const bf16x8*)(vga + (jj + 1) * 64);
            vpf[1] = *(const bf16x8*)(vga + (jj + 1) * 64 + 131072);
        }

        const bool active = (jj * 64 <= qrow_wmax);   // wave-uniform
        if (active) {
            // S^T = K Q^T (swapped): D[m = kpos-in-tile][n = lane&15 = q-row]
            f32x4 s_acc[4] = {};
            __builtin_amdgcn_s_setprio(1);
            #pragma unroll
            for (int nt = 0; nt < 4; nt++) {
                #pragma unroll
                for (int kk = 0; kk < 4; kk++) {
                    bf16x8 bk = *(const bf16x8*)(sKb + (nt * 16 + row) * 256
                                                 + (((kk * 4 + quad) * 16) ^ rx));
                    s_acc[nt] = __builtin_amdgcn_mfma_f32_16x16x32_bf16(
                        bk, aq[kk], s_acc[nt], 0, 0, 0);
                }
            }
            __builtin_amdgcn_s_setprio(0);

            // scale + causal mask (only when tile straddles the diagonal)
            const bool needmask = (jj * 64 + 63 > qrow_wmin);
            #pragma unroll
            for (int nt = 0; nt < 4; nt++) {
                #pragma unroll
                for (int v = 0; v < 4; v++) {
                    float s = s_acc[nt][v] * scale;
                    if (needmask) {
                        int kpos = jj * 64 + nt * 16 + quad * 4 + v;
                        if (kpos > qrow_lane) s = -1e30f;
                    }
                    s_acc[nt][v] = s;
                }
            }
            // row max: in-lane over 16 + 2 shfl (across quads)
            float m_loc = s_acc[0][0];
            #pragma unroll
            for (int nt = 0; nt < 4; nt++)
                #pragma unroll
                for (int v = 0; v < 4; v++)
                    m_loc = fmaxf(m_loc, s_acc[nt][v]);
            m_loc = fmaxf(m_loc, __shfl_xor(m_loc, 16, 64));
            m_loc = fmaxf(m_loc, __shfl_xor(m_loc, 32, 64));

            // T13 defer-max: only rescale when max grew past THR=8
            if (!__all(m_loc - pm <= 8.0f)) {
                float mn = fmaxf(pm, m_loc);
                float al = __expf(pm - mn);
                pm = mn;
                pl *= al;
                float al_q[4];
                #pragma unroll
                for (int v = 0; v < 4; v++)
                    al_q[v] = __shfl(al, quad * 4 + v, 64);
                #pragma unroll
                for (int dt = 0; dt < 8; dt++)
                    #pragma unroll
                    for (int v = 0; v < 4; v++)
                        o_acc[dt][v] *= al_q[v];
            }

            // P = exp(S - pm): b64 writes, slot = 2nt+(quad>>1) XOR (row&7),
            // intra-slot (quad&1)*8. Reads use the same involution.
            float rs = 0.0f;
            #pragma unroll
            for (int nt = 0; nt < 4; nt++) {
                bf16x4 pw;
                #pragma unroll
                for (int v = 0; v < 4; v++) {
                    float p = __expf(s_acc[nt][v] - pm);
                    rs += p;
                    bf16 pb = (bf16)p;
                    pw[v] = *(short*)&pb;
                }
                int slot = (2 * nt + (quad >> 1)) ^ (row & 7);
                *(bf16x4*)(sPb + (wave * 16 + row) * 128 + slot * 16 + (quad & 1) * 8) = pw;
            }
            rs += __shfl_xor(rs, 16, 64);
            rs += __shfl_xor(rs, 32, 64);
            pl += rs;

            // O += P V
            __builtin_amdgcn_s_setprio(1);
            #pragma unroll
            for (int kk = 0; kk < 2; kk++) {
                bf16x8 pa = *(const bf16x8*)(sPb + (wave * 16 + row) * 128
                                             + (((kk * 4 + quad) * 16) ^ rx));
                #pragma unroll
                for (int dt = 0; dt < 8; dt++) {
                    bf16x8 vb = *(const bf16x8*)(sVb + (dt * 16 + row) * 128
                                                 + (((kk * 4 + quad) * 16) ^ rx));
                    o_acc[dt] = __builtin_amdgcn_mfma_f32_16x16x32_bf16(
                        pa, vb, o_acc[dt], 0, 0, 0);
                }
            }
            __builtin_amdgcn_s_setprio(0);
        }

        // T14 write-late: drain prefetched regs into LDS (linear, conflict-free)
        if (jj < NJ - 1) {
            __syncthreads();    // all waves done reading sK/sV of tile jj
            *(bf16x8*)(sKb + ldst)        = kpf[0];
            *(bf16x8*)(sKb + ldst + 8192) = kpf[1];
            *(bf16x8*)(sVb + ldst)        = vpf[0];
            *(bf16x8*)(sVb + ldst + 8192) = vpf[1];
            __syncthreads();    // tile jj+1 visible
        }
    }

    // epilogue: O / l. o_acc row = quad*4+v -> fetch pl for those rows.
    float pl_q[4];
    #pragma unroll
    for (int v = 0; v < 4; v++)
        pl_q[v] = __shfl(pl, quad * 4 + v, 64);
    const int token = b * 2048 + qt * 128 + wave * 16;
    #pragma unroll
    for (int dt = 0; dt < 8; dt++) {
        #pragma unroll
        for (int v = 0; v < 4; v++) {
            float o = o_acc[dt][v] / pl_q[v];
            int trow = token + quad * 4 + v;
            Oout[(size_t)trow * 4096 + h * 128 + dt * 16 + row] = (bf16)o;
        }
    }
}

// ---------------------------------------------------------------------------
// Workspace plan (peak 128 MB; all regions fully rewritten each call):
//   0..32   xb (x as bf16)   -> later overwritten by attn output
//   32..80  Wqkvb            -> after GEMM1: Qb(32..64) Kb(64..72) VTb(72..80)
//   80..128 qkv              -> after rope:  Woutb(80..112)
// d_out is FLOAT32 (reference output dtype) — 64 MB.
// ---------------------------------------------------------------------------
extern "C" void kernel_launch(void* const* d_in, const int* in_sizes, int n_in,
                              void* d_out, int out_size, void* d_ws, size_t ws_size,
                              hipStream_t stream) {
    float* out = (float*)d_out;                // (2,2048,4096) float32

    const size_t MB = 1024 * 1024;
    char* ws = (char*)d_ws;
    bf16* xb    = (bf16*)(ws);                 // 0..32 MB
    bf16* Wqkvb = (bf16*)(ws + 32 * MB);       // 32..80 MB
    bf16* qkv   = (bf16*)(ws + 80 * MB);       // 80..128 MB
    bf16* Qb    = (bf16*)(ws + 32 * MB);       // over dead Wqkvb
    bf16* Kb    = (bf16*)(ws + 64 * MB);
    bf16* VTb   = (bf16*)(ws + 72 * MB);
    bf16* Woutb = (bf16*)(ws + 80 * MB);       // over dead qkv
    bf16* attn  = xb;                          // over dead xb

    convert_to_bf16<<<8192,  256, 0, stream>>>(d_in[0], xb,    16777216L);
    convert_to_bf16<<<12288, 256, 0, stream>>>(d_in[1], Wqkvb, 25165824L);
    // 1) qkv = clip(x @ Wqkv^T, +-8)  — BN=192: 32x16 grid = 2 FULL rounds
    gemm256<192, true, bf16><<<dim3(32, 16), 512, 0, stream>>>(xb, Wqkvb, qkv, 4096, 6144, 4096);
    // 2) rope + reorder (reads 80..128, writes 32..80)
    rope_reorder<<<dim3(12, 4096), 256, 0, stream>>>(qkv, Qb, Kb, VTb);
    // (qkv now dead; stage Wout there)
    convert_to_bf16<<<8192,  256, 0, stream>>>(d_in[2], Woutb, 16777216L);
    // 3) causal GQA flash attention -> attn[token][4096] (reads 32..80, writes 0..32)
    attn_kernel<<<dim3(64, 16), 512, 0, stream>>>(Qb, Kb, VTb, attn);
    // 4) out = attn @ Wout^T            (FLOAT out -> d_out)
    gemm256<256, false, float><<<dim3(16, 16), 512, 0, stream>>>(attn, Woutb, out, 4096, 4096, 4096);
}

// Round 8
// 771.066 us; speedup vs baseline: 1.2707x; 1.2707x over previous
//
#include <hip/hip_runtime.h>
#include <hip/hip_bf16.h>
#include <math.h>

typedef __hip_bfloat16 bf16;
typedef __attribute__((ext_vector_type(8))) short bf16x8;   // 8 bf16 = 4 VGPRs (MFMA A/B frag)
typedef __attribute__((ext_vector_type(4))) short bf16x4;   // 4 bf16 = 8 bytes
typedef __attribute__((ext_vector_type(4))) float f32x4;    // MFMA C/D frag

__device__ __forceinline__ void glds16(const bf16* g, bf16* l) {
    __builtin_amdgcn_global_load_lds(
        (const __attribute__((address_space(1))) void*)g,
        (__attribute__((address_space(3))) void*)l, 16, 0, 0);
}

// ---------------------------------------------------------------------------
// Self-detecting convert: each wave inspects the tensor's first 128 ushorts.
// ---------------------------------------------------------------------------
__global__ __launch_bounds__(256)
void convert_to_bf16(const void* __restrict__ src, bf16* __restrict__ dst, long n) {
    const unsigned short* u16 = (const unsigned short*)src;
    int lane = threadIdx.x & 63;
    unsigned short u = u16[lane * 2];
    int e = (u >> 7) & 0xFF;
    int isf32 = __popcll(__ballot(e >= 0x86)) > 4;   // wave-uniform
    long i = ((long)blockIdx.x * 256 + threadIdx.x) * 8;
    if (i >= n) return;
    if (isf32) {
        const float* s = (const float*)src;
        bf16x8 o;
        #pragma unroll
        for (int j = 0; j < 8; j++) {
            bf16 b = (bf16)s[i + j];
            o[j] = *(short*)&b;
        }
        *(bf16x8*)(dst + i) = o;
    } else {
        *(bf16x8*)(dst + i) = *(const bf16x8*)((const bf16*)src + i);
    }
}

// ---------------------------------------------------------------------------
// GEMM (round 6, verified): 256xBN tile, BK=64, 8 waves, dbuf LDS, counted
// vmcnt/lgkm pipeline, T2 source-side swizzle (0 conflicts), T1, T5.
// ---------------------------------------------------------------------------
template<int BN, bool CLIP, typename OUT>
__global__ __launch_bounds__(512, 2)
void gemm256(const bf16* __restrict__ A, const bf16* __restrict__ B,
             OUT* __restrict__ C, int M, int N, int K) {
    constexpr int NB = BN / 64;          // B frags per k-step, B stage issues
    constexpr int WN = BN / 4;           // per-wave N span
    __shared__ __align__(16) bf16 sA[2][256 * 64];
    __shared__ __align__(16) bf16 sB[2][BN * 64];

    const int tid   = threadIdx.x;
    const int lane  = tid & 63;
    const int row16 = lane & 15;
    const int quad  = lane >> 4;
    const int wid   = tid >> 6;
    const int wr    = wid >> 2;          // 0..1  (M half)
    const int wc    = wid & 3;           // 0..3  (N quarter)

    // T1: XCD-aware bijective swizzle (grids here are multiples of 8)
    const int nwg  = gridDim.x * gridDim.y;
    const int orig = blockIdx.y * gridDim.x + blockIdx.x;
    const int cpx  = nwg >> 3;
    const int sw   = (orig & 7) * cpx + (orig >> 3);
    const int bn   = sw % gridDim.x;
    const int bm   = sw / gridDim.x;

    // Staging: linear LDS dest (tid*16 B), source chunk = slot ^ (row&7).
    const int srow   = tid >> 3;                 // 0..63
    const int schunk = (tid & 7) ^ (srow & 7);
    const bf16* gA = A + (size_t)(bm * 256) * K + schunk * 8;
    const bf16* gB = B + (size_t)(bn * BN) * K + schunk * 8;

    auto STAGE = [&](int u, int t) {
        #pragma unroll
        for (int q = 0; q < 4; q++)
            glds16(gA + (size_t)(q * 64 + srow) * K + t * 64,
                   &sA[u][0] + q * 4096 + tid * 8);
        #pragma unroll
        for (int q = 0; q < NB; q++)
            glds16(gB + (size_t)(q * 64 + srow) * K + t * 64,
                   &sB[u][0] + q * 4096 + tid * 8);
    };

    // Fragment read bases (bytes); chunk c of row r sits at slot c^(r&7).
    const int cx0 = ((quad) ^ (row16 & 7)) << 4;
    const int cx1 = ((4 + quad) ^ (row16 & 7)) << 4;
    const int aRowOff = (wr * 128 + row16) * 128;
    const int bRowOff = (wc * WN + row16) * 128;

    f32x4 acc[8][NB] = {};

    const int NT = K >> 6;               // 64-wide K-tiles
    STAGE(0, 0);
    STAGE(1, 1);
    if constexpr (NB == 4) asm volatile("s_waitcnt vmcnt(8)" ::: "memory");
    else                   asm volatile("s_waitcnt vmcnt(7)" ::: "memory");
    __builtin_amdgcn_sched_barrier(0);
    __builtin_amdgcn_s_barrier();

    for (int t = 0; t < NT; t++) {
        const int cur = t & 1;
        const char* aRd = (const char*)(&sA[cur][0]) + aRowOff;
        const char* bRd = (const char*)(&sB[cur][0]) + bRowOff;

        // issue ks0 reads (8+NB), then ks1 reads (8+NB), order pinned
        bf16x8 af0[8], bf0[NB], af1[8], bf1[NB];
        #pragma unroll
        for (int i = 0; i < 8; i++)
            af0[i] = *(const bf16x8*)(aRd + i * 2048 + cx0);
        #pragma unroll
        for (int j = 0; j < NB; j++)
            bf0[j] = *(const bf16x8*)(bRd + j * 2048 + cx0);
        __builtin_amdgcn_sched_barrier(0);      // group boundary (lgkm count!)
        #pragma unroll
        for (int i = 0; i < 8; i++)
            af1[i] = *(const bf16x8*)(aRd + i * 2048 + cx1);
        #pragma unroll
        for (int j = 0; j < NB; j++)
            bf1[j] = *(const bf16x8*)(bRd + j * 2048 + cx1);
        __builtin_amdgcn_sched_barrier(0);

        // wait first group only (DS completes in-order per wave)
        if constexpr (NB == 4) asm volatile("s_waitcnt lgkmcnt(12)" ::: "memory");
        else                   asm volatile("s_waitcnt lgkmcnt(11)" ::: "memory");
        __builtin_amdgcn_sched_barrier(0);

        __builtin_amdgcn_s_setprio(1);
        #pragma unroll
        for (int i = 0; i < 8; i++)
            #pragma unroll
            for (int j = 0; j < NB; j++)
                acc[i][j] = __builtin_amdgcn_mfma_f32_16x16x32_bf16(
                    af0[i], bf0[j], acc[i][j], 0, 0, 0);
        __builtin_amdgcn_s_setprio(0);
        __builtin_amdgcn_sched_barrier(0);

        asm volatile("s_waitcnt lgkmcnt(0)" ::: "memory");
        __builtin_amdgcn_sched_barrier(0);
        __builtin_amdgcn_s_barrier();        // all waves done reading buf[cur]

        if (t + 2 < NT) STAGE(cur, t + 2);
        __builtin_amdgcn_sched_barrier(0);   // keep glds issued before MFMA

        __builtin_amdgcn_s_setprio(1);
        #pragma unroll
        for (int i = 0; i < 8; i++)
            #pragma unroll
            for (int j = 0; j < NB; j++)
                acc[i][j] = __builtin_amdgcn_mfma_f32_16x16x32_bf16(
                    af1[i], bf1[j], acc[i][j], 0, 0, 0);
        __builtin_amdgcn_s_setprio(0);
        __builtin_amdgcn_sched_barrier(0);

        if (t + 2 < NT) {
            if constexpr (NB == 4) asm volatile("s_waitcnt vmcnt(8)" ::: "memory");
            else                   asm volatile("s_waitcnt vmcnt(7)" ::: "memory");
        } else {
            asm volatile("s_waitcnt vmcnt(0)" ::: "memory");
        }
        __builtin_amdgcn_sched_barrier(0);
        __builtin_amdgcn_s_barrier();        // buf[cur^1] (tile t+1) visible
    }

    // epilogue: C/D layout col = lane&15, row = quad*4+v  [m89/m91]
    #pragma unroll
    for (int i = 0; i < 8; i++) {
        #pragma unroll
        for (int j = 0; j < NB; j++) {
            #pragma unroll
            for (int v = 0; v < 4; v++) {
                float val = acc[i][j][v];
                if (CLIP) val = fminf(fmaxf(val, -8.0f), 8.0f);
                int grow = bm * 256 + wr * 128 + i * 16 + quad * 4 + v;
                int gcol = bn * BN + wc * WN + j * 16 + row16;
                C[(size_t)grow * N + gcol] = (OUT)val;
            }
        }
    }
}

// ---------------------------------------------------------------------------
// RoPE + reorder: qkv[token][6144] -> Q[b][32][l][128] (roped),
// K[b][8][l][128] (roped), VT[b][8][128][l] (transposed copy).
// ---------------------------------------------------------------------------
__global__ __launch_bounds__(256)
void rope_reorder(const bf16* __restrict__ qkv, bf16* __restrict__ Q,
                  bf16* __restrict__ Kd, bf16* __restrict__ VT) {
    const int token = blockIdx.y;                          // 0..4095
    const int slot  = blockIdx.x * 4 + (threadIdx.x >> 6); // 0..47
    const int lane  = threadIdx.x & 63;
    const int b = token >> 11, l = token & 2047;
    const bf16* src = qkv + (size_t)token * 6144 + slot * 128;
    if (slot < 40) {
        float x1 = __bfloat162float(src[lane]);
        float x2 = __bfloat162float(src[lane + 64]);
        float inv_freq = powf(500000.0f, -(float)lane * (1.0f / 64.0f));
        float ang = (float)l * inv_freq;
        float s, c;
        sincosf(ang, &s, &c);
        float o1 = x1 * c - x2 * s;
        float o2 = x2 * c + x1 * s;
        bf16* dst;
        if (slot < 32) dst = Q  + ((size_t)(b * 32 + slot)        * 2048 + l) * 128;
        else           dst = Kd + ((size_t)(b * 8  + (slot - 32)) * 2048 + l) * 128;
        dst[lane]      = (bf16)o1;
        dst[lane + 64] = (bf16)o2;
    } else {
        bf16* dst = VT + (size_t)(b * 8 + (slot - 40)) * 128 * 2048 + l;
        dst[(size_t)lane * 2048]        = src[lane];
        dst[(size_t)(lane + 64) * 2048] = src[lane + 64];
    }
}

// ---------------------------------------------------------------------------
// Flash attention, causal, GQA 4:1. Round 8 = round 7 structure (8 waves,
// 128-row Q tiles, shared 64-kpos K/V staging, swapped QK^T, in-reg softmax,
// T13, T14) with the SPILL FIXED:
//   - launch_bounds(512, 4): VGPR cap 128 (round 7's (512,6) capped at ~85,
//     spilling o_acc -> 762 MB scratch writes/dispatch, VGPR_Count=40).
//     2 blocks/CU = 16 waves/CU, still > round 6's 12.
//   - grid x = qt (fast dim) again: consecutive blocks share one K/V panel
//     (round 6's FETCH=74MB proved the L2 locality); LPT via qt=15-bx.
// ---------------------------------------------------------------------------
__global__ __launch_bounds__(512, 4)
void attn_kernel(const bf16* __restrict__ Q, const bf16* __restrict__ K,
                 const bf16* __restrict__ V, bf16* __restrict__ Oout) {
    const int qt = 15 - blockIdx.x;     // LPT: big tiles first within a head
    const int bh = blockIdx.y;          // 0..63
    const int b = bh >> 5, h = bh & 31;
    const int kh = h >> 2;              // GQA: head h uses kv-head h/4
    const bf16* Qp = Q + ((size_t)(b * 32 + h) * 2048 + qt * 128) * 128;
    const bf16* Kp = K + (size_t)(b * 8 + kh) * 2048 * 128;
    const bf16* Vp = V + (size_t)(b * 8 + kh) * 128 * 2048;   // [d][l]

    __shared__ __align__(16) bf16 sK[64 * 128];    // 16 KB, source-swizzled
    __shared__ __align__(16) bf16 sV[128 * 64];    // 16 KB, source-swizzled
    __shared__ __align__(16) bf16 sP[8 * 16 * 64]; // 16 KB, XOR-swizzled

    const int tid = threadIdx.x, lane = tid & 63, wave = tid >> 6;
    const int row = lane & 15, quad = lane >> 4;
    const int rx  = (row & 7) << 4;      // read-side XOR (byte bits 4..6)
    char* sKb = (char*)sK;
    char* sVb = (char*)sV;
    char* sPb = (char*)sP;

    // Staging (512 threads, 2 passes each): linear LDS dest, swizzled source.
    const int kr0 = tid >> 4;
    const int kc8 = (tid & 15) ^ (kr0 & 7);
    const int vr0 = tid >> 3;
    const int vc8 = (tid & 7) ^ (vr0 & 7);
    const int ldst = tid * 16;
    const bf16* kga = Kp + (size_t)kr0 * 128 + kc8 * 8;   // + jj*8192 (+4096 pass1)
    const bf16* vga = Vp + (size_t)vr0 * 2048 + vc8 * 8;  // + jj*64  (+131072 pass1)

    // Q fragments straight to registers (this wave's 16 q-rows), read once.
    bf16x8 aq[4];
    #pragma unroll
    for (int kk = 0; kk < 4; kk++)
        aq[kk] = *(const bf16x8*)(Qp + (size_t)(wave * 16 + row) * 128 + (kk * 4 + quad) * 8);

    // prologue: stage tile 0
    bf16x8 kpf[2], vpf[2];
    kpf[0] = *(const bf16x8*)(kga);
    kpf[1] = *(const bf16x8*)(kga + 4096);
    vpf[0] = *(const bf16x8*)(vga);
    vpf[1] = *(const bf16x8*)(vga + 131072);
    *(bf16x8*)(sKb + ldst)        = kpf[0];
    *(bf16x8*)(sKb + ldst + 8192) = kpf[1];
    *(bf16x8*)(sVb + ldst)        = vpf[0];
    *(bf16x8*)(sVb + ldst + 8192) = vpf[1];
    __syncthreads();

    float pm = -1e30f, pl = 0.0f;       // per-lane stats for q-row lane&15
    f32x4 o_acc[8] = {};
    const float scale = 0.08838834764831845f;   // 1/sqrt(128)
    const int NJ = 2 * qt + 2;
    const int qrow_lane = qt * 128 + wave * 16 + row;   // this lane's q-row
    const int qrow_wmin = qt * 128 + wave * 16;
    const int qrow_wmax = qrow_wmin + 15;

    for (int jj = 0; jj < NJ; jj++) {
        // T14: issue next tile's loads EARLY (used only after the barrier)
        if (jj < NJ - 1) {
            kpf[0] = *(const bf16x8*)(kga + (size_t)(jj + 1) * 8192);
            kpf[1] = *(const bf16x8*)(kga + (size_t)(jj + 1) * 8192 + 4096);
            vpf[0] = *(const bf16x8*)(vga + (jj + 1) * 64);
            vpf[1] = *(const bf16x8*)(vga + (jj + 1) * 64 + 131072);
        }

        const bool active = (jj * 64 <= qrow_wmax);   // wave-uniform
        if (active) {
            // S^T = K Q^T (swapped): D[m = kpos-in-tile][n = lane&15 = q-row]
            f32x4 s_acc[4] = {};
            __builtin_amdgcn_s_setprio(1);
            #pragma unroll
            for (int nt = 0; nt < 4; nt++) {
                #pragma unroll
                for (int kk = 0; kk < 4; kk++) {
                    bf16x8 bk = *(const bf16x8*)(sKb + (nt * 16 + row) * 256
                                                 + (((kk * 4 + quad) * 16) ^ rx));
                    s_acc[nt] = __builtin_amdgcn_mfma_f32_16x16x32_bf16(
                        bk, aq[kk], s_acc[nt], 0, 0, 0);
                }
            }
            __builtin_amdgcn_s_setprio(0);

            // scale + causal mask (only when tile straddles the diagonal)
            const bool needmask = (jj * 64 + 63 > qrow_wmin);
            #pragma unroll
            for (int nt = 0; nt < 4; nt++) {
                #pragma unroll
                for (int v = 0; v < 4; v++) {
                    float s = s_acc[nt][v] * scale;
                    if (needmask) {
                        int kpos = jj * 64 + nt * 16 + quad * 4 + v;
                        if (kpos > qrow_lane) s = -1e30f;
                    }
                    s_acc[nt][v] = s;
                }
            }
            // row max: in-lane over 16 + 2 shfl (across quads)
            float m_loc = s_acc[0][0];
            #pragma unroll
            for (int nt = 0; nt < 4; nt++)
                #pragma unroll
                for (int v = 0; v < 4; v++)
                    m_loc = fmaxf(m_loc, s_acc[nt][v]);
            m_loc = fmaxf(m_loc, __shfl_xor(m_loc, 16, 64));
            m_loc = fmaxf(m_loc, __shfl_xor(m_loc, 32, 64));

            // T13 defer-max: only rescale when max grew past THR=8
            if (!__all(m_loc - pm <= 8.0f)) {
                float mn = fmaxf(pm, m_loc);
                float al = __expf(pm - mn);
                pm = mn;
                pl *= al;
                float al_q[4];
                #pragma unroll
                for (int v = 0; v < 4; v++)
                    al_q[v] = __shfl(al, quad * 4 + v, 64);
                #pragma unroll
                for (int dt = 0; dt < 8; dt++)
                    #pragma unroll
                    for (int v = 0; v < 4; v++)
                        o_acc[dt][v] *= al_q[v];
            }

            // P = exp(S - pm): b64 writes, slot = (2nt+(quad>>1)) XOR (row&7),
            // intra-slot (quad&1)*8. Reads use the same involution.
            float rs = 0.0f;
            #pragma unroll
            for (int nt = 0; nt < 4; nt++) {
                bf16x4 pw;
                #pragma unroll
                for (int v = 0; v < 4; v++) {
                    float p = __expf(s_acc[nt][v] - pm);
                    rs += p;
                    bf16 pb = (bf16)p;
                    pw[v] = *(short*)&pb;
                }
                int slot = (2 * nt + (quad >> 1)) ^ (row & 7);
                *(bf16x4*)(sPb + (wave * 16 + row) * 128 + slot * 16 + (quad & 1) * 8) = pw;
            }
            rs += __shfl_xor(rs, 16, 64);
            rs += __shfl_xor(rs, 32, 64);
            pl += rs;

            // O += P V
            __builtin_amdgcn_s_setprio(1);
            #pragma unroll
            for (int kk = 0; kk < 2; kk++) {
                bf16x8 pa = *(const bf16x8*)(sPb + (wave * 16 + row) * 128
                                             + (((kk * 4 + quad) * 16) ^ rx));
                #pragma unroll
                for (int dt = 0; dt < 8; dt++) {
                    bf16x8 vb = *(const bf16x8*)(sVb + (dt * 16 + row) * 128
                                                 + (((kk * 4 + quad) * 16) ^ rx));
                    o_acc[dt] = __builtin_amdgcn_mfma_f32_16x16x32_bf16(
                        pa, vb, o_acc[dt], 0, 0, 0);
                }
            }
            __builtin_amdgcn_s_setprio(0);
        }

        // T14 write-late: drain prefetched regs into LDS (linear, conflict-free)
        if (jj < NJ - 1) {
            __syncthreads();    // all waves done reading sK/sV of tile jj
            *(bf16x8*)(sKb + ldst)        = kpf[0];
            *(bf16x8*)(sKb + ldst + 8192) = kpf[1];
            *(bf16x8*)(sVb + ldst)        = vpf[0];
            *(bf16x8*)(sVb + ldst + 8192) = vpf[1];
            __syncthreads();    // tile jj+1 visible
        }
    }

    // epilogue: O / l. o_acc row = quad*4+v -> fetch pl for those rows.
    float pl_q[4];
    #pragma unroll
    for (int v = 0; v < 4; v++)
        pl_q[v] = __shfl(pl, quad * 4 + v, 64);
    const int token = b * 2048 + qt * 128 + wave * 16;
    #pragma unroll
    for (int dt = 0; dt < 8; dt++) {
        #pragma unroll
        for (int v = 0; v < 4; v++) {
            float o = o_acc[dt][v] / pl_q[v];
            int trow = token + quad * 4 + v;
            Oout[(size_t)trow * 4096 + h * 128 + dt * 16 + row] = (bf16)o;
        }
    }
}

// ---------------------------------------------------------------------------
// Workspace plan (peak 128 MB; all regions fully rewritten each call):
//   0..32   xb (x as bf16)   -> later overwritten by attn output
//   32..80  Wqkvb            -> after GEMM1: Qb(32..64) Kb(64..72) VTb(72..80)
//   80..128 qkv              -> after rope:  Woutb(80..112)
// d_out is FLOAT32 (reference output dtype) — 64 MB.
// ---------------------------------------------------------------------------
extern "C" void kernel_launch(void* const* d_in, const int* in_sizes, int n_in,
                              void* d_out, int out_size, void* d_ws, size_t ws_size,
                              hipStream_t stream) {
    float* out = (float*)d_out;                // (2,2048,4096) float32

    const size_t MB = 1024 * 1024;
    char* ws = (char*)d_ws;
    bf16* xb    = (bf16*)(ws);                 // 0..32 MB
    bf16* Wqkvb = (bf16*)(ws + 32 * MB);       // 32..80 MB
    bf16* qkv   = (bf16*)(ws + 80 * MB);       // 80..128 MB
    bf16* Qb    = (bf16*)(ws + 32 * MB);       // over dead Wqkvb
    bf16* Kb    = (bf16*)(ws + 64 * MB);
    bf16* VTb   = (bf16*)(ws + 72 * MB);
    bf16* Woutb = (bf16*)(ws + 80 * MB);       // over dead qkv
    bf16* attn  = xb;                          // over dead xb

    convert_to_bf16<<<8192,  256, 0, stream>>>(d_in[0], xb,    16777216L);
    convert_to_bf16<<<12288, 256, 0, stream>>>(d_in[1], Wqkvb, 25165824L);
    // 1) qkv = clip(x @ Wqkv^T, +-8)  — BN=192: 32x16 grid = 2 FULL rounds
    gemm256<192, true, bf16><<<dim3(32, 16), 512, 0, stream>>>(xb, Wqkvb, qkv, 4096, 6144, 4096);
    // 2) rope + reorder (reads 80..128, writes 32..80)
    rope_reorder<<<dim3(12, 4096), 256, 0, stream>>>(qkv, Qb, Kb, VTb);
    // (qkv now dead; stage Wout there)
    convert_to_bf16<<<8192,  256, 0, stream>>>(d_in[2], Woutb, 16777216L);
    // 3) causal GQA flash attention -> attn[token][4096] (reads 32..80, writes 0..32)
    attn_kernel<<<dim3(16, 64), 512, 0, stream>>>(Qb, Kb, VTb, attn);
    // 4) out = attn @ Wout^T            (FLOAT out -> d_out)
    gemm256<256, false, float><<<dim3(16, 16), 512, 0, stream>>>(attn, Woutb, out, 4096, 4096, 4096);
}